// Round 3
// baseline (366.131 us; speedup 1.0000x reference)
//
#include <hip/hip_runtime.h>

#define HWSZ 16384
#define CIN 96
#define ICTOT 288
#define OUT_S_ELEMS (8*96*16384)
#define TILE_USH (ICTOT*32)          // 9216 ushorts = 18432 B per A k-tile
#define NTILES 81

typedef __attribute__((ext_vector_type(8))) short bf16x8;
typedef __attribute__((ext_vector_type(4))) float f32x4;

#define VMCNT(n) asm volatile("s_waitcnt vmcnt(" #n ")" ::: "memory")
#define LGKM0    asm volatile("s_waitcnt lgkmcnt(0)" ::: "memory")

__device__ __forceinline__ unsigned short f2bf(float f){
  unsigned int u = __float_as_uint(f);
  u += 0x7FFFu + ((u >> 16) & 1u);
  return (unsigned short)(u >> 16);
}

__device__ __forceinline__ void gload16(const unsigned short* g, const unsigned short* l){
  __builtin_amdgcn_global_load_lds(
      (const __attribute__((address_space(1))) unsigned int*)g,
      (__attribute__((address_space(3))) unsigned int*)l, 16, 0, 0);
}

// ---- build filter tiles WbT[j][oc][cc_swizzled], j = chunk*9 + tap ----
// swizzle: 16B block index cc>>3 XORed with (oc>>1)&3 (T2, matches conv read)
__global__ void pack_w_kernel(const float* __restrict__ w_ss, const float* __restrict__ w_sv,
                              const float* __restrict__ w_vs, const float* __restrict__ w_vv,
                              const float* __restrict__ f_k0, const float* __restrict__ f_k1,
                              const float* __restrict__ f_k2, unsigned short* __restrict__ WbT){
  int idx = blockIdx.x*256 + threadIdx.x;
  if (idx >= NTILES*ICTOT*32) return;
  int j = idx / (ICTOT*32); int rem = idx - j*(ICTOT*32);
  int oc = rem >> 5, cc = rem & 31;
  int tap = j % 9, cch = j / 9;
  int ic = cch*32 + cc;
  float acc = 0.f;
  if (oc < 96){
    int o = oc;
    if (ic < CIN){
      int i = ic;
      for (int n=0;n<3;++n) acc += w_ss[(o*CIN+i)*3+n]*f_k0[n*9+tap];
    } else {
      int v = ic-CIN; int i=v>>1, a=v&1;
      for (int n=0;n<4;++n) acc += w_vs[(o*CIN+i)*4+n]*f_k1[(n*9+tap)*2+a];
    }
  } else {
    int ov = oc-96; int o=ov>>1, c=ov&1;
    if (ic < CIN){
      int i = ic;
      for (int n=0;n<4;++n) acc += w_sv[(o*CIN+i)*4+n]*f_k1[(n*9+tap)*2+c];
    } else {
      int v = ic-CIN; int i=v>>1, a=v&1;
      for (int n=0;n<5;++n) acc += w_vv[(o*CIN+i)*5+n]*f_k2[((n*9+tap)*2+a)*2+c];
    }
  }
  int cc_sw = ((((cc>>3) ^ ((oc>>1)&3)) << 3) | (cc & 7));
  WbT[(size_t)j*TILE_USH + oc*32 + cc_sw] = f2bf(acc);
}

// ---- pack x_scalar -> Xp[b][p][ic] (ic 0..95), bf16 + per-channel sums ----
__global__ void pack_xs_kernel(const float* __restrict__ xs, unsigned short* __restrict__ Xp,
                               float* __restrict__ Ssum){
  __shared__ float tile[32][65];
  int bid = blockIdx.x;
  int ct = bid % 3; int pt = (bid/3) & 255; int b = bid / 768;
  int p0 = pt*64, c0 = ct*32;
  int t = threadIdx.x;
  int cl = t >> 6, pl = t & 63;
  for (int kk=0; kk<8; ++kk){
    int c = kk*4 + cl;
    tile[c][pl] = xs[(size_t)(b*CIN + c0 + c)*HWSZ + p0 + pl];
  }
  __syncthreads();
  int c = t & 31, pw = t >> 5;
  float psum = 0.f;
  for (int j=0;j<8;++j){
    int p = pw*8 + j;
    float v = tile[c][p];
    psum += v;
    Xp[(size_t)(b*HWSZ + p0 + p)*ICTOT + c0 + c] = f2bf(v);
  }
  psum += __shfl_xor(psum, 32);
  if ((t & 32) == 0) atomicAdd(&Ssum[b*ICTOT + c0 + c], psum);
}

// ---- pack x_vector -> Xp[b][p][96 + 2i + a] + per-channel sums ----
__global__ void pack_xv_kernel(const float* __restrict__ xv, unsigned short* __restrict__ Xp,
                               float* __restrict__ Ssum){
  __shared__ float2 tile[32][65];
  int bid = blockIdx.x;
  int ct = bid % 3; int pt = (bid/3) & 255; int b = bid / 768;
  int p0 = pt*64, c0 = ct*32;
  int t = threadIdx.x;
  int cl = t >> 6, pl = t & 63;
  const float2* src = (const float2*)xv;
  for (int kk=0; kk<8; ++kk){
    int c = kk*4 + cl;
    tile[c][pl] = src[(size_t)(b*CIN + c0 + c)*HWSZ + p0 + pl];
  }
  __syncthreads();
  int c = t & 31, pw = t >> 5;
  float sx = 0.f, sy = 0.f;
  for (int j=0;j<8;++j){
    int p = pw*8 + j;
    float2 v = tile[c][p];
    sx += v.x; sy += v.y;
    unsigned int u = (unsigned int)f2bf(v.x) | ((unsigned int)f2bf(v.y) << 16);
    *(unsigned int*)&Xp[(size_t)(b*HWSZ + p0 + p)*ICTOT + CIN + 2*(c0+c)] = u;
  }
  sx += __shfl_xor(sx, 32);
  sy += __shfl_xor(sy, 32);
  if ((t & 32) == 0){
    atomicAdd(&Ssum[b*ICTOT + CIN + 2*(c0+c)    ], sx);
    atomicAdd(&Ssum[b*ICTOT + CIN + 2*(c0+c) + 1], sy);
  }
}

// ---- analytic mean-bias: MB[b][row] = b_v[o] * mean(out_v[b,o,:,:,c]) ----
// torus conv: mean(out) = (sum_tap F) . mean(x)
__global__ void mbias_kernel(const float* __restrict__ w_sv, const float* __restrict__ w_vv,
                             const float* __restrict__ f_k1, const float* __restrict__ f_k2,
                             const float* __restrict__ b_v, const float* __restrict__ Ssum,
                             float* __restrict__ MB){
  int row = blockIdx.x;              // 0..191 ; row = 2o + c
  int o = row >> 1, c = row & 1;
  int lane = threadIdx.x;            // 64
  float f1s[4], f2s[5][2];
  for (int n=0;n<4;++n){
    float s=0.f;
    for (int tap=0;tap<9;++tap) s += f_k1[(n*9+tap)*2+c];
    f1s[n]=s;
  }
  for (int n=0;n<5;++n)
    for (int a=0;a<2;++a){
      float s=0.f;
      for (int tap=0;tap<9;++tap) s += f_k2[((n*9+tap)*2+a)*2+c];
      f2s[n][a]=s;
    }
  float wv[5];
  for (int k=0;k<5;++k){
    int ic = lane + 64*k;
    float v = 0.f;
    if (ic < CIN){
      for (int n=0;n<4;++n) v += w_sv[(o*CIN+ic)*4+n]*f1s[n];
    } else if (ic < ICTOT){
      int u = ic-CIN; int i=u>>1, a=u&1;
      for (int n=0;n<5;++n) v += w_vv[(o*CIN+i)*5+n]*f2s[n][a];
    }
    wv[k] = v;
  }
  for (int b=0;b<8;++b){
    float acc = 0.f;
    for (int k=0;k<5;++k){
      int ic = lane + 64*k;
      if (ic < ICTOT) acc += wv[k]*Ssum[b*ICTOT+ic];
    }
    for (int m=1;m<64;m<<=1) acc += __shfl_xor(acc, m);
    if (lane == 0) MB[b*192+row] = b_v[o]*acc*(1.f/16384.f);
  }
}

// ---- conv: block = 288 oc x 256 px (2 image rows), 8 waves, 81 K-phases ----
__global__ __launch_bounds__(512,2) void conv_mfma_kernel(
    const unsigned short* __restrict__ Xp, const unsigned short* __restrict__ WbT,
    const float* __restrict__ b_s, const float* __restrict__ MB,
    float* __restrict__ out){
  __shared__ unsigned short Ash[3][1536*8];   // 3 x 24576 B (top 6KB staging slop)
  __shared__ unsigned short Bsh[2][2048*8];   // 2 x 32768 B

  int bid = blockIdx.x;
  int b = bid & 7, rp = bid >> 3;             // batch -> XCD, row-pair 0..63
  int tid = threadIdx.x;
  int lane = tid & 63, w = tid >> 6;
  int wr = w >> 2, wc = w & 3;                // wave tile: 144 oc x 64 px
  int cl = lane & 15, g = lane >> 4;

  f32x4 acc[9][4];
  #pragma unroll
  for (int m=0;m<9;++m)
    #pragma unroll
    for (int n=0;n<4;++n) acc[m][n] = (f32x4){0.f,0.f,0.f,0.f};

  // B-stage source pointers, pre-swizzled per-lane (T2 via m173 pattern)
  const size_t xb = (size_t)b * HWSZ * ICTOT;
  const unsigned short* srcB[4];
  #pragma unroll
  for (int i=0;i<4;++i){
    int f = i*512 + tid;
    int j = f >> 9, px = (f >> 2) & 127, cp = f & 3;
    int cps = cp ^ ((px >> 1) & 3);
    int hs = (2*rp - 1 + j + 128) & 127;
    srcB[i] = Xp + xb + ((size_t)(hs*128 + px))*ICTOT + cps*8;
  }
  const unsigned short* srcA = WbT + tid*8;
  const int wlds = w*64*8;                    // wave-uniform LDS chunk base (ushorts)
  const int Abase = (wr*144 + cl)*32 + ((g ^ ((cl>>1)&3))*8);  // swizzled A frag addr
  const int pxb = (wc & 1)*64 + cl;
  const int jr0 = (wc >> 1);

  // prologue: B(0), A(0), A(1)
  #pragma unroll
  for (int i=0;i<4;++i) gload16(srcB[i], &Bsh[0][i*512*8 + wlds]);
  #pragma unroll
  for (int i=0;i<3;++i) gload16(srcA + 0*TILE_USH + i*4096, &Ash[0][i*512*8 + wlds]);
  #pragma unroll
  for (int i=0;i<3;++i) gload16(srcA + 1*TILE_USH + i*4096, &Ash[1][i*512*8 + wlds]);
  VMCNT(3);                                   // B(0), A(0) landed; A(1) in flight
  __builtin_amdgcn_s_barrier();

  const unsigned short* cA = srcA;            // advances 9 tiles per chunk iter
  for (int c = 0; c < 9; ++c){
    const unsigned short* Bcur = Bsh[c & 1];
    unsigned short* Bnxt = (unsigned short*)Bsh[(c & 1) ^ 1];
    #pragma unroll
    for (int t = 0; t < 9; ++t){
      if (c < 8 || t <= 6){
        #pragma unroll
        for (int i=0;i<3;++i)
          gload16(cA + (t+2)*TILE_USH + i*4096, &Ash[(t+2)%3][i*512*8 + wlds]);
      }
      if (t == 0 && c < 8){
        #pragma unroll
        for (int i=0;i<4;++i)
          gload16(srcB[i] + (c+1)*32, &Bnxt[i*512*8 + wlds]);
      }
      const int ky = t / 3, kx = t % 3;
      const int jbase = (jr0 + ky)*4096;      // halo-row base (ushorts)
      bf16x8 bfr[4];
      #pragma unroll
      for (int n=0;n<4;++n){
        int px = (pxb + n*16 + kx + 127) & 127;
        int blk = g ^ ((px >> 1) & 3);
        bfr[n] = *(const bf16x8*)&Bcur[jbase + px*32 + blk*8];
      }
      const unsigned short* At = Ash[t % 3];
      __builtin_amdgcn_s_setprio(1);
      #pragma unroll
      for (int m=0;m<9;++m){
        bf16x8 af = *(const bf16x8*)&At[Abase + m*512];
        #pragma unroll
        for (int n=0;n<4;++n)
          acc[m][n] = __builtin_amdgcn_mfma_f32_16x16x32_bf16(af, bfr[n], acc[m][n], 0,0,0);
      }
      __builtin_amdgcn_s_setprio(0);
      LGKM0;                                  // my frag reads retired
      if (t <= 1){ if (c < 8) { VMCNT(7); } else { VMCNT(3); } }
      else if (t >= 7){ if (c == 8) { VMCNT(0); } else { VMCNT(3); } }
      else { VMCNT(3); }
      __builtin_amdgcn_sched_barrier(0);
      __builtin_amdgcn_s_barrier();
    }
    cA += 9*TILE_USH;
  }

  // epilogue
  const int orow = 2*rp + (wc >> 1);
  const int colb = (wc & 1)*64;
  #pragma unroll
  for (int m=0;m<9;++m){
    int ocb = wr*144 + m*16 + 4*g;            // rows ocb..ocb+3
    if (wr == 0 && m < 6){
      #pragma unroll
      for (int r=0;r<4;++r){
        int oc = ocb + r;
        float bias = b_s[oc];
        #pragma unroll
        for (int n=0;n<4;++n){
          int p = orow*128 + colb + n*16 + cl;
          out[(size_t)(b*96+oc)*HWSZ + p] = acc[m][n][r] + bias;
        }
      }
    } else {
      float2* outv = (float2*)(out + OUT_S_ELEMS);
      int row0 = ocb - 96;                    // even
      int o0 = row0 >> 1;
      float mb0 = MB[b*192+row0  ], mb1 = MB[b*192+row0+1];
      float mb2 = MB[b*192+row0+2], mb3 = MB[b*192+row0+3];
      #pragma unroll
      for (int n=0;n<4;++n){
        int p = orow*128 + colb + n*16 + cl;
        outv[(size_t)(b*96+o0  )*HWSZ + p] = (float2){acc[m][n][0]+mb0, acc[m][n][1]+mb1};
        outv[(size_t)(b*96+o0+1)*HWSZ + p] = (float2){acc[m][n][2]+mb2, acc[m][n][3]+mb3};
      }
    }
  }
}

extern "C" void kernel_launch(void* const* d_in, const int* in_sizes, int n_in,
                              void* d_out, int out_size, void* d_ws, size_t ws_size,
                              hipStream_t stream){
  const float* xs   = (const float*)d_in[0];
  const float* xv   = (const float*)d_in[1];
  const float* f_k0 = (const float*)d_in[2];
  const float* f_k1 = (const float*)d_in[3];
  const float* f_k2 = (const float*)d_in[4];
  const float* w_ss = (const float*)d_in[5];
  const float* w_sv = (const float*)d_in[6];
  const float* w_vs = (const float*)d_in[7];
  const float* w_vv = (const float*)d_in[8];
  const float* b_s  = (const float*)d_in[9];
  const float* b_v  = (const float*)d_in[10];
  float* out = (float*)d_out;

  char* ws = (char*)d_ws;
  unsigned short* WbT = (unsigned short*)ws;                 // 1,492,992 B (+6144 slop)
  const size_t XP_OFF = (size_t)NTILES*TILE_USH*2 + 6144;    // 1,499,136
  unsigned short* Xp = (unsigned short*)(ws + XP_OFF);
  const size_t SSUM_OFF = XP_OFF + (size_t)8*HWSZ*ICTOT*2;   // + 75,497,472
  float* Ssum = (float*)(ws + SSUM_OFF);                     // 8*288*4 = 9216 B
  float* MB   = (float*)(ws + SSUM_OFF + 9216);              // 8*192*4 = 6144 B

  hipMemsetAsync(Ssum, 0, 8*ICTOT*sizeof(float), stream);
  pack_w_kernel<<<(NTILES*ICTOT*32 + 255)/256, 256, 0, stream>>>(
      w_ss, w_sv, w_vs, w_vv, f_k0, f_k1, f_k2, WbT);
  pack_xs_kernel<<<6144, 256, 0, stream>>>(xs, Xp, Ssum);
  pack_xv_kernel<<<6144, 256, 0, stream>>>(xv, Xp, Ssum);
  mbias_kernel<<<192, 64, 0, stream>>>(w_sv, w_vv, f_k1, f_k2, b_v, Ssum, MB);
  conv_mfma_kernel<<<512, 512, 0, stream>>>(Xp, WbT, b_s, MB, out);
}

// Round 4
// 257.056 us; speedup vs baseline: 1.4243x; 1.4243x over previous
//
#include <hip/hip_runtime.h>

#define HWSZ 16384
#define CIN 96
#define ICTOT 288
#define OUT_S_ELEMS (8*96*16384)
#define TILE_USH (ICTOT*32)          // 9216 ushorts = 18432 B per A k-tile
#define NTILES 81

typedef __attribute__((ext_vector_type(8))) short bf16x8;
typedef __attribute__((ext_vector_type(4))) float f32x4;

#define VMCNT(n) asm volatile("s_waitcnt vmcnt(" #n ")" ::: "memory")

__device__ __forceinline__ unsigned short f2bf(float f){
  unsigned int u = __float_as_uint(f);
  u += 0x7FFFu + ((u >> 16) & 1u);
  return (unsigned short)(u >> 16);
}

__device__ __forceinline__ void gload16(const unsigned short* g, const unsigned short* l){
  __builtin_amdgcn_global_load_lds(
      (const __attribute__((address_space(1))) unsigned int*)g,
      (__attribute__((address_space(3))) unsigned int*)l, 16, 0, 0);
}

// ---- build filter tiles WbT[j][oc][cc_swizzled], j = chunk*9 + tap ----
__global__ void pack_w_kernel(const float* __restrict__ w_ss, const float* __restrict__ w_sv,
                              const float* __restrict__ w_vs, const float* __restrict__ w_vv,
                              const float* __restrict__ f_k0, const float* __restrict__ f_k1,
                              const float* __restrict__ f_k2, unsigned short* __restrict__ WbT){
  int idx = blockIdx.x*256 + threadIdx.x;
  if (idx >= NTILES*ICTOT*32) return;
  int j = idx / (ICTOT*32); int rem = idx - j*(ICTOT*32);
  int oc = rem >> 5, cc = rem & 31;
  int tap = j % 9, cch = j / 9;
  int ic = cch*32 + cc;
  float acc = 0.f;
  if (oc < 96){
    int o = oc;
    if (ic < CIN){
      int i = ic;
      for (int n=0;n<3;++n) acc += w_ss[(o*CIN+i)*3+n]*f_k0[n*9+tap];
    } else {
      int v = ic-CIN; int i=v>>1, a=v&1;
      for (int n=0;n<4;++n) acc += w_vs[(o*CIN+i)*4+n]*f_k1[(n*9+tap)*2+a];
    }
  } else {
    int ov = oc-96; int o=ov>>1, c=ov&1;
    if (ic < CIN){
      int i = ic;
      for (int n=0;n<4;++n) acc += w_sv[(o*CIN+i)*4+n]*f_k1[(n*9+tap)*2+c];
    } else {
      int v = ic-CIN; int i=v>>1, a=v&1;
      for (int n=0;n<5;++n) acc += w_vv[(o*CIN+i)*5+n]*f_k2[((n*9+tap)*2+a)*2+c];
    }
  }
  int cc_sw = ((((cc>>3) ^ ((oc>>1)&3)) << 3) | (cc & 7));
  WbT[(size_t)j*TILE_USH + oc*32 + cc_sw] = f2bf(acc);
}

// ---- pack x_scalar -> Xp[b][p][ic] + per-block channel partials (no atomics) ----
__global__ void pack_xs_kernel(const float* __restrict__ xs, unsigned short* __restrict__ Xp,
                               float* __restrict__ Part){
  __shared__ float tile[32][65];
  __shared__ float red[8][32];
  int bid = blockIdx.x;
  int ct = bid % 3; int pt = (bid/3) & 255; int b = bid / 768;
  int p0 = pt*64, c0 = ct*32;
  int t = threadIdx.x;
  int cl = t >> 6, pl = t & 63;
  for (int kk=0; kk<8; ++kk){
    int c = kk*4 + cl;
    tile[c][pl] = xs[(size_t)(b*CIN + c0 + c)*HWSZ + p0 + pl];
  }
  __syncthreads();
  int c = t & 31, pw = t >> 5;
  float psum = 0.f;
  for (int j=0;j<8;++j){
    int p = pw*8 + j;
    float v = tile[c][p];
    psum += v;
    Xp[(size_t)(b*HWSZ + p0 + p)*ICTOT + c0 + c] = f2bf(v);
  }
  red[pw][c] = psum;
  __syncthreads();
  if (t < 32){
    float s = 0.f;
    #pragma unroll
    for (int k=0;k<8;++k) s += red[k][t];
    Part[((size_t)b*ICTOT + c0 + t)*256 + pt] = s;
  }
}

// ---- pack x_vector -> Xp[b][p][96 + 2i + a] + partials ----
__global__ void pack_xv_kernel(const float* __restrict__ xv, unsigned short* __restrict__ Xp,
                               float* __restrict__ Part){
  __shared__ float2 tile[32][65];
  __shared__ float redx[8][32], redy[8][32];
  int bid = blockIdx.x;
  int ct = bid % 3; int pt = (bid/3) & 255; int b = bid / 768;
  int p0 = pt*64, c0 = ct*32;
  int t = threadIdx.x;
  int cl = t >> 6, pl = t & 63;
  const float2* src = (const float2*)xv;
  for (int kk=0; kk<8; ++kk){
    int c = kk*4 + cl;
    tile[c][pl] = src[(size_t)(b*CIN + c0 + c)*HWSZ + p0 + pl];
  }
  __syncthreads();
  int c = t & 31, pw = t >> 5;
  float sx = 0.f, sy = 0.f;
  for (int j=0;j<8;++j){
    int p = pw*8 + j;
    float2 v = tile[c][p];
    sx += v.x; sy += v.y;
    unsigned int u = (unsigned int)f2bf(v.x) | ((unsigned int)f2bf(v.y) << 16);
    *(unsigned int*)&Xp[(size_t)(b*HWSZ + p0 + p)*ICTOT + CIN + 2*(c0+c)] = u;
  }
  redx[pw][c] = sx; redy[pw][c] = sy;
  __syncthreads();
  if (t < 32){
    float s0 = 0.f, s1 = 0.f;
    #pragma unroll
    for (int k=0;k<8;++k){ s0 += redx[k][t]; s1 += redy[k][t]; }
    Part[((size_t)b*ICTOT + CIN + 2*(c0+t)    )*256 + pt] = s0;
    Part[((size_t)b*ICTOT + CIN + 2*(c0+t) + 1)*256 + pt] = s1;
  }
}

// ---- Ssum[b][ch] = sum over 256 partials ----
__global__ void reduce_part_kernel(const float* __restrict__ Part, float* __restrict__ Ssum){
  int b = blockIdx.x;                // 8 blocks x 320 threads
  int t = threadIdx.x;
  if (t >= ICTOT) return;
  const float* p = Part + ((size_t)b*ICTOT + t)*256;
  float s = 0.f;
  #pragma unroll 8
  for (int i=0;i<256;++i) s += p[i];
  Ssum[b*ICTOT + t] = s;
}

// ---- analytic mean-bias: MB[b][row] = b_v[o] * mean(out_v[b,o,:,:,c]) ----
__global__ void mbias_kernel(const float* __restrict__ w_sv, const float* __restrict__ w_vv,
                             const float* __restrict__ f_k1, const float* __restrict__ f_k2,
                             const float* __restrict__ b_v, const float* __restrict__ Ssum,
                             float* __restrict__ MB){
  int row = blockIdx.x;              // 0..191 ; row = 2o + c
  int o = row >> 1, c = row & 1;
  int lane = threadIdx.x;            // 64
  float f1s[4], f2s[5][2];
  for (int n=0;n<4;++n){
    float s=0.f;
    for (int tap=0;tap<9;++tap) s += f_k1[(n*9+tap)*2+c];
    f1s[n]=s;
  }
  for (int n=0;n<5;++n)
    for (int a=0;a<2;++a){
      float s=0.f;
      for (int tap=0;tap<9;++tap) s += f_k2[((n*9+tap)*2+a)*2+c];
      f2s[n][a]=s;
    }
  float wv[5];
  for (int k=0;k<5;++k){
    int ic = lane + 64*k;
    float v = 0.f;
    if (ic < CIN){
      for (int n=0;n<4;++n) v += w_sv[(o*CIN+ic)*4+n]*f1s[n];
    } else if (ic < ICTOT){
      int u = ic-CIN; int i=u>>1, a=u&1;
      for (int n=0;n<5;++n) v += w_vv[(o*CIN+i)*5+n]*f2s[n][a];
    }
    wv[k] = v;
  }
  for (int b=0;b<8;++b){
    float acc = 0.f;
    for (int k=0;k<5;++k){
      int ic = lane + 64*k;
      if (ic < ICTOT) acc += wv[k]*Ssum[b*ICTOT+ic];
    }
    for (int m=1;m<64;m<<=1) acc += __shfl_xor(acc, m);
    if (lane == 0) MB[b*192+row] = b_v[o]*acc*(1.f/16384.f);
  }
}

// ---- conv: block = 288 oc x 256 px (2 image rows), 8 waves, 81 K-phases ----
__global__ __launch_bounds__(512,2) void conv_mfma_kernel(
    const unsigned short* __restrict__ Xp, const unsigned short* __restrict__ WbT,
    const float* __restrict__ b_s, const float* __restrict__ MB,
    float* __restrict__ out){
  __shared__ unsigned short Ash[3][1536*8];   // 3 x 24576 B (top 6KB staging slop)
  __shared__ unsigned short Bsh[2][2048*8];   // 2 x 32768 B

  int bid = blockIdx.x;
  int b = bid & 7, rp = bid >> 3;             // batch -> XCD, row-pair 0..63
  int tid = threadIdx.x;
  int lane = tid & 63, w = tid >> 6;
  int wr = w >> 2, wc = w & 3;                // wave tile: 144 oc x 64 px
  int cl = lane & 15, g = lane >> 4;

  f32x4 acc[9][4];
  #pragma unroll
  for (int m=0;m<9;++m)
    #pragma unroll
    for (int n=0;n<4;++n) acc[m][n] = (f32x4){0.f,0.f,0.f,0.f};

  // B-stage source pointers, pre-swizzled per-lane (T2 via m173 pattern)
  const size_t xb = (size_t)b * HWSZ * ICTOT;
  const unsigned short* srcB[4];
  #pragma unroll
  for (int i=0;i<4;++i){
    int f = i*512 + tid;
    int j = f >> 9, px = (f >> 2) & 127, cp = f & 3;
    int cps = cp ^ ((px >> 1) & 3);
    int hs = (2*rp - 1 + j + 128) & 127;
    srcB[i] = Xp + xb + ((size_t)(hs*128 + px))*ICTOT + cps*8;
  }
  const unsigned short* srcA = WbT + tid*8;
  const int wlds = w*64*8;                    // wave-uniform LDS chunk base (ushorts)
  const int Abase = (wr*144 + cl)*32 + ((g ^ ((cl>>1)&3))*8);  // swizzled A frag addr
  const int pxb = (wc & 1)*64 + cl;
  const int jr0 = (wc >> 1);

  // loop-invariant B fragment offsets (12 VGPRs, static-indexed)
  int boff[3][4];
  #pragma unroll
  for (int kx=0;kx<3;++kx)
    #pragma unroll
    for (int n=0;n<4;++n){
      int px = (pxb + n*16 + kx + 127) & 127;
      boff[kx][n] = px*32 + ((g ^ ((px >> 1) & 3))*8);
    }

  // prologue: B(0), A(0), A(1)
  #pragma unroll
  for (int i=0;i<4;++i) gload16(srcB[i], &Bsh[0][i*512*8 + wlds]);
  #pragma unroll
  for (int i=0;i<3;++i) gload16(srcA + 0*TILE_USH + i*4096, &Ash[0][i*512*8 + wlds]);
  #pragma unroll
  for (int i=0;i<3;++i) gload16(srcA + 1*TILE_USH + i*4096, &Ash[1][i*512*8 + wlds]);
  VMCNT(3);                                   // B(0), A(0) landed; A(1) in flight
  __builtin_amdgcn_s_barrier();

  const unsigned short* cA = srcA;            // advances 9 tiles per chunk iter
  for (int c = 0; c < 9; ++c){
    const unsigned short* Bcur = Bsh[c & 1];
    unsigned short* Bnxt = (unsigned short*)Bsh[(c & 1) ^ 1];
    #pragma unroll
    for (int t = 0; t < 9; ++t){
      if (c < 8 || t <= 6){
        #pragma unroll
        for (int i=0;i<3;++i)
          gload16(cA + (t+2)*TILE_USH + i*4096, &Ash[(t+2)%3][i*512*8 + wlds]);
      }
      if (t == 0 && c < 8){
        #pragma unroll
        for (int i=0;i<4;++i)
          gload16(srcB[i] + (c+1)*32, &Bnxt[i*512*8 + wlds]);
      }
      const int ky = t / 3, kx = t % 3;
      const unsigned short* Bj = Bcur + (jr0 + ky)*4096;
      bf16x8 bfr[4];
      #pragma unroll
      for (int n=0;n<4;++n) bfr[n] = *(const bf16x8*)&Bj[boff[kx][n]];
      const unsigned short* At = Ash[t % 3];
      __builtin_amdgcn_s_setprio(1);
      #pragma unroll
      for (int m=0;m<9;++m){
        bf16x8 af = *(const bf16x8*)&At[Abase + m*512];
        #pragma unroll
        for (int n=0;n<4;++n)
          acc[m][n] = __builtin_amdgcn_mfma_f32_16x16x32_bf16(af, bfr[n], acc[m][n], 0,0,0);
      }
      __builtin_amdgcn_s_setprio(0);
      if (t <= 1){ if (c < 8) { VMCNT(7); } else { VMCNT(3); } }
      else if (t >= 7){ if (c == 8) { VMCNT(0); } else { VMCNT(3); } }
      else { VMCNT(3); }
      __builtin_amdgcn_sched_barrier(0);
      __builtin_amdgcn_s_barrier();
    }
    cA += 9*TILE_USH;
  }

  // epilogue
  const int orow = 2*rp + (wc >> 1);
  const int colb = (wc & 1)*64;
  #pragma unroll
  for (int m=0;m<9;++m){
    int ocb = wr*144 + m*16 + 4*g;            // rows ocb..ocb+3
    if (wr == 0 && m < 6){
      #pragma unroll
      for (int r=0;r<4;++r){
        int oc = ocb + r;
        float bias = b_s[oc];
        #pragma unroll
        for (int n=0;n<4;++n){
          int p = orow*128 + colb + n*16 + cl;
          out[(size_t)(b*96+oc)*HWSZ + p] = acc[m][n][r] + bias;
        }
      }
    } else {
      float2* outv = (float2*)(out + OUT_S_ELEMS);
      int row0 = ocb - 96;                    // even
      int o0 = row0 >> 1;
      float mb0 = MB[b*192+row0  ], mb1 = MB[b*192+row0+1];
      float mb2 = MB[b*192+row0+2], mb3 = MB[b*192+row0+3];
      #pragma unroll
      for (int n=0;n<4;++n){
        int p = orow*128 + colb + n*16 + cl;
        outv[(size_t)(b*96+o0  )*HWSZ + p] = (float2){acc[m][n][0]+mb0, acc[m][n][1]+mb1};
        outv[(size_t)(b*96+o0+1)*HWSZ + p] = (float2){acc[m][n][2]+mb2, acc[m][n][3]+mb3};
      }
    }
  }
}

extern "C" void kernel_launch(void* const* d_in, const int* in_sizes, int n_in,
                              void* d_out, int out_size, void* d_ws, size_t ws_size,
                              hipStream_t stream){
  const float* xs   = (const float*)d_in[0];
  const float* xv   = (const float*)d_in[1];
  const float* f_k0 = (const float*)d_in[2];
  const float* f_k1 = (const float*)d_in[3];
  const float* f_k2 = (const float*)d_in[4];
  const float* w_ss = (const float*)d_in[5];
  const float* w_sv = (const float*)d_in[6];
  const float* w_vs = (const float*)d_in[7];
  const float* w_vv = (const float*)d_in[8];
  const float* b_s  = (const float*)d_in[9];
  const float* b_v  = (const float*)d_in[10];
  float* out = (float*)d_out;

  char* ws = (char*)d_ws;
  unsigned short* WbT = (unsigned short*)ws;                 // 1,492,992 B (+6144 slop)
  const size_t XP_OFF = (size_t)NTILES*TILE_USH*2 + 6144;    // 1,499,136
  unsigned short* Xp = (unsigned short*)(ws + XP_OFF);
  const size_t PART_OFF = XP_OFF + (size_t)8*HWSZ*ICTOT*2;   // + 75,497,472
  float* Part = (float*)(ws + PART_OFF);                     // 8*288*256*4 = 2,359,296 B
  float* Ssum = (float*)(ws + PART_OFF + 2359296);           // 9216 B
  float* MB   = (float*)(ws + PART_OFF + 2359296 + 9216);    // 6144 B

  pack_w_kernel<<<(NTILES*ICTOT*32 + 255)/256, 256, 0, stream>>>(
      w_ss, w_sv, w_vs, w_vv, f_k0, f_k1, f_k2, WbT);
  pack_xs_kernel<<<6144, 256, 0, stream>>>(xs, Xp, Part);
  pack_xv_kernel<<<6144, 256, 0, stream>>>(xv, Xp, Part);
  reduce_part_kernel<<<8, 320, 0, stream>>>(Part, Ssum);
  mbias_kernel<<<192, 64, 0, stream>>>(w_sv, w_vv, f_k1, f_k2, b_v, Ssum, MB);
  conv_mfma_kernel<<<512, 512, 0, stream>>>(Xp, WbT, b_s, MB, out);
}

// Round 5
// 240.015 us; speedup vs baseline: 1.5255x; 1.0710x over previous
//
#include <hip/hip_runtime.h>

#define HWSZ 16384
#define CIN 96
#define ICTOT 288
#define OUT_S_ELEMS (8*96*16384)
#define TILE_USH (ICTOT*32)          // 9216 ushorts = 18432 B per A k-tile
#define NTILES 81

typedef __attribute__((ext_vector_type(8))) short bf16x8;
typedef __attribute__((ext_vector_type(4))) float f32x4;

#define VMCNT(n) asm volatile("s_waitcnt vmcnt(" #n ")" ::: "memory")

__device__ __forceinline__ unsigned short f2bf(float f){
  unsigned int u = __float_as_uint(f);
  u += 0x7FFFu + ((u >> 16) & 1u);
  return (unsigned short)(u >> 16);
}

__device__ __forceinline__ void gload16(const unsigned short* g, const unsigned short* l){
  __builtin_amdgcn_global_load_lds(
      (const __attribute__((address_space(1))) unsigned int*)g,
      (__attribute__((address_space(3))) unsigned int*)l, 16, 0, 0);
}

// ---- build filter tiles WbT[j][oc][cc_swizzled], j = chunk*9 + tap ----
__global__ void pack_w_kernel(const float* __restrict__ w_ss, const float* __restrict__ w_sv,
                              const float* __restrict__ w_vs, const float* __restrict__ w_vv,
                              const float* __restrict__ f_k0, const float* __restrict__ f_k1,
                              const float* __restrict__ f_k2, unsigned short* __restrict__ WbT){
  int idx = blockIdx.x*256 + threadIdx.x;
  if (idx >= NTILES*ICTOT*32) return;
  int j = idx / (ICTOT*32); int rem = idx - j*(ICTOT*32);
  int oc = rem >> 5, cc = rem & 31;
  int tap = j % 9, cch = j / 9;
  int ic = cch*32 + cc;
  float acc = 0.f;
  if (oc < 96){
    int o = oc;
    if (ic < CIN){
      int i = ic;
      for (int n=0;n<3;++n) acc += w_ss[(o*CIN+i)*3+n]*f_k0[n*9+tap];
    } else {
      int v = ic-CIN; int i=v>>1, a=v&1;
      for (int n=0;n<4;++n) acc += w_vs[(o*CIN+i)*4+n]*f_k1[(n*9+tap)*2+a];
    }
  } else {
    int ov = oc-96; int o=ov>>1, c=ov&1;
    if (ic < CIN){
      int i = ic;
      for (int n=0;n<4;++n) acc += w_sv[(o*CIN+i)*4+n]*f_k1[(n*9+tap)*2+c];
    } else {
      int v = ic-CIN; int i=v>>1, a=v&1;
      for (int n=0;n<5;++n) acc += w_vv[(o*CIN+i)*5+n]*f_k2[((n*9+tap)*2+a)*2+c];
    }
  }
  int cc_sw = ((((cc>>3) ^ ((oc>>1)&3)) << 3) | (cc & 7));
  WbT[(size_t)j*TILE_USH + oc*32 + cc_sw] = f2bf(acc);
}

// ---- merged pack: blocks [0,6144) = x_scalar, [6144,12288) = x_vector ----
__global__ void pack_x_kernel(const float* __restrict__ xs, const float* __restrict__ xv,
                              unsigned short* __restrict__ Xp, float* __restrict__ Part){
  __shared__ float2 tile[32][65];
  __shared__ float red[2][8][32];
  int bid0 = blockIdx.x;
  int t = threadIdx.x;
  if (bid0 < 6144){
    int bid = bid0;
    int ct = bid % 3; int pt = (bid/3) & 255; int b = bid / 768;
    int p0 = pt*64, c0 = ct*32;
    float* tf = (float*)tile;              // [32][130] float view, use first 64+pad
    int cl = t >> 6, pl = t & 63;
    for (int kk=0; kk<8; ++kk){
      int c = kk*4 + cl;
      tf[c*130 + pl] = xs[(size_t)(b*CIN + c0 + c)*HWSZ + p0 + pl];
    }
    __syncthreads();
    int c = t & 31, pw = t >> 5;
    float psum = 0.f;
    for (int j=0;j<8;++j){
      int p = pw*8 + j;
      float v = tf[c*130 + p];
      psum += v;
      Xp[(size_t)(b*HWSZ + p0 + p)*ICTOT + c0 + c] = f2bf(v);
    }
    red[0][pw][c] = psum;
    __syncthreads();
    if (t < 32){
      float s = 0.f;
      #pragma unroll
      for (int k=0;k<8;++k) s += red[0][k][t];
      Part[((size_t)b*ICTOT + c0 + t)*256 + pt] = s;
    }
  } else {
    int bid = bid0 - 6144;
    int ct = bid % 3; int pt = (bid/3) & 255; int b = bid / 768;
    int p0 = pt*64, c0 = ct*32;
    int cl = t >> 6, pl = t & 63;
    const float2* src = (const float2*)xv;
    for (int kk=0; kk<8; ++kk){
      int c = kk*4 + cl;
      tile[c][pl] = src[(size_t)(b*CIN + c0 + c)*HWSZ + p0 + pl];
    }
    __syncthreads();
    int c = t & 31, pw = t >> 5;
    float sx = 0.f, sy = 0.f;
    for (int j=0;j<8;++j){
      int p = pw*8 + j;
      float2 v = tile[c][p];
      sx += v.x; sy += v.y;
      unsigned int u = (unsigned int)f2bf(v.x) | ((unsigned int)f2bf(v.y) << 16);
      *(unsigned int*)&Xp[(size_t)(b*HWSZ + p0 + p)*ICTOT + CIN + 2*(c0+c)] = u;
    }
    red[0][pw][c] = sx; red[1][pw][c] = sy;
    __syncthreads();
    if (t < 32){
      float s0 = 0.f, s1 = 0.f;
      #pragma unroll
      for (int k=0;k<8;++k){ s0 += red[0][k][t]; s1 += red[1][k][t]; }
      Part[((size_t)b*ICTOT + CIN + 2*(c0+t)    )*256 + pt] = s0;
      Part[((size_t)b*ICTOT + CIN + 2*(c0+t) + 1)*256 + pt] = s1;
    }
  }
}

// ---- Ssum[b][ch] = sum over 256 partials ----
__global__ void reduce_part_kernel(const float* __restrict__ Part, float* __restrict__ Ssum){
  int b = blockIdx.x;                // 8 blocks x 320 threads
  int t = threadIdx.x;
  if (t >= ICTOT) return;
  const float* p = Part + ((size_t)b*ICTOT + t)*256;
  float s = 0.f;
  #pragma unroll 8
  for (int i=0;i<256;++i) s += p[i];
  Ssum[b*ICTOT + t] = s;
}

// ---- analytic mean-bias: MB[b][row] = b_v[o] * mean(out_v[b,o,:,:,c]) ----
__global__ void mbias_kernel(const float* __restrict__ w_sv, const float* __restrict__ w_vv,
                             const float* __restrict__ f_k1, const float* __restrict__ f_k2,
                             const float* __restrict__ b_v, const float* __restrict__ Ssum,
                             float* __restrict__ MB){
  int row = blockIdx.x;              // 0..191 ; row = 2o + c
  int o = row >> 1, c = row & 1;
  int lane = threadIdx.x;            // 64
  float f1s[4], f2s[5][2];
  for (int n=0;n<4;++n){
    float s=0.f;
    for (int tap=0;tap<9;++tap) s += f_k1[(n*9+tap)*2+c];
    f1s[n]=s;
  }
  for (int n=0;n<5;++n)
    for (int a=0;a<2;++a){
      float s=0.f;
      for (int tap=0;tap<9;++tap) s += f_k2[((n*9+tap)*2+a)*2+c];
      f2s[n][a]=s;
    }
  float wv[5];
  for (int k=0;k<5;++k){
    int ic = lane + 64*k;
    float v = 0.f;
    if (ic < CIN){
      for (int n=0;n<4;++n) v += w_sv[(o*CIN+ic)*4+n]*f1s[n];
    } else if (ic < ICTOT){
      int u = ic-CIN; int i=u>>1, a=u&1;
      for (int n=0;n<5;++n) v += w_vv[(o*CIN+i)*5+n]*f2s[n][a];
    }
    wv[k] = v;
  }
  for (int b=0;b<8;++b){
    float acc = 0.f;
    for (int k=0;k<5;++k){
      int ic = lane + 64*k;
      if (ic < ICTOT) acc += wv[k]*Ssum[b*ICTOT+ic];
    }
    for (int m=1;m<64;m<<=1) acc += __shfl_xor(acc, m);
    if (lane == 0) MB[b*192+row] = b_v[o]*acc*(1.f/16384.f);
  }
}

// ---- conv: block = 288 oc x 256 px, 8 waves, 81 K-phases, frag-prefetch pipeline ----
__global__ __launch_bounds__(512,2) void conv_mfma_kernel(
    const unsigned short* __restrict__ Xp, const unsigned short* __restrict__ WbT,
    const float* __restrict__ b_s, const float* __restrict__ MB,
    float* __restrict__ out){
  __shared__ unsigned short Ash[3][1536*8];   // 3 x 24576 B (top 6KB staging slop)
  __shared__ unsigned short Bsh[2][2048*8];   // 2 x 32768 B

  int bid = blockIdx.x;
  int b = bid & 7, rp = bid >> 3;             // batch -> XCD, row-pair 0..63
  int tid = threadIdx.x;
  int lane = tid & 63, w = tid >> 6;
  int wr = w >> 2, wc = w & 3;                // wave tile: 144 oc x 64 px
  int cl = lane & 15, g = lane >> 4;

  f32x4 acc[9][4];
  #pragma unroll
  for (int m=0;m<9;++m)
    #pragma unroll
    for (int n=0;n<4;++n) acc[m][n] = (f32x4){0.f,0.f,0.f,0.f};

  // B-stage source pointers, pre-swizzled per-lane (T2 via m173 pattern)
  const size_t xb = (size_t)b * HWSZ * ICTOT;
  const unsigned short* srcB[4];
  #pragma unroll
  for (int i=0;i<4;++i){
    int f = i*512 + tid;
    int j = f >> 9, px = (f >> 2) & 127, cp = f & 3;
    int cps = cp ^ ((px >> 1) & 3);
    int hs = (2*rp - 1 + j + 128) & 127;
    srcB[i] = Xp + xb + ((size_t)(hs*128 + px))*ICTOT + cps*8;
  }
  const unsigned short* srcA = WbT + tid*8;
  const int wlds = w*64*8;                    // wave-uniform LDS chunk base (ushorts)
  const int Abase = (wr*144 + cl)*32 + ((g ^ ((cl>>1)&3))*8);  // swizzled A frag addr
  const int pxb = (wc & 1)*64 + cl;
  const int jr0 = (wc >> 1);

  // loop-invariant B fragment offsets (static-indexed)
  int boff[3][4];
  #pragma unroll
  for (int kx=0;kx<3;++kx)
    #pragma unroll
    for (int n=0;n<4;++n){
      int px = (pxb + n*16 + kx + 127) & 127;
      boff[kx][n] = px*32 + ((g ^ ((px >> 1) & 3))*8);
    }

  // prologue: B(0), A(0), A(1); full drain; pre-read phase-0 fragments
  #pragma unroll
  for (int i=0;i<4;++i) gload16(srcB[i], &Bsh[0][i*4096 + wlds]);
  #pragma unroll
  for (int i=0;i<3;++i) gload16(srcA + 0*TILE_USH + i*4096, &Ash[0][i*4096 + wlds]);
  #pragma unroll
  for (int i=0;i<3;++i) gload16(srcA + 1*TILE_USH + i*4096, &Ash[1][i*4096 + wlds]);
  VMCNT(0);
  __builtin_amdgcn_s_barrier();

  bf16x8 afc[9], bfc[4];
  #pragma unroll
  for (int n=0;n<4;++n) bfc[n] = *(const bf16x8*)&Bsh[0][jr0*4096 + boff[0][n]];
  #pragma unroll
  for (int m=0;m<9;++m) afc[m] = *(const bf16x8*)&Ash[0][Abase + m*512];

  const unsigned short* cA = srcA;            // advances 9 tiles per chunk iter
  for (int c = 0; c < 9; ++c){
    const unsigned short* Bcur = Bsh[c & 1];
    unsigned short* Bnxt = (unsigned short*)Bsh[(c & 1) ^ 1];
    #pragma unroll
    for (int t = 0; t < 9; ++t){
      // 1) issue stages: A(g+2), and B(c+1) at t==0
      if (c < 8 || t <= 6){
        #pragma unroll
        for (int i=0;i<3;++i)
          gload16(cA + (t+2)*TILE_USH + i*4096, &Ash[(t+2)%3][i*4096 + wlds]);
      }
      if (t == 0 && c < 8){
        #pragma unroll
        for (int i=0;i<4;++i)
          gload16(srcB[i] + (c+1)*32, &Bnxt[i*4096 + wlds]);
      }
      // 2) MFMA on previously-read fragments (register-only, no LDS wait)
      __builtin_amdgcn_s_setprio(1);
      #pragma unroll
      for (int m=0;m<9;++m){
        #pragma unroll
        for (int n=0;n<4;++n)
          acc[m][n] = __builtin_amdgcn_mfma_f32_16x16x32_bf16(afc[m], bfc[n], acc[m][n], 0,0,0);
      }
      __builtin_amdgcn_s_setprio(0);
      // 3) vmcnt gate: A(g+1) (and any needed B) landed before next-frag reads
      if (c < 8){ if (t <= 1) { VMCNT(7); } else { VMCNT(3); } }
      else      { if (t <= 6) { VMCNT(3); } else if (t == 7) { VMCNT(0); } }
      // 4) read next phase's fragments (refill same regs; WAR on this phase's MFMAs)
      if (c < 8 || t < 8){
        const int tau = (t+1)%9;
        const int ky = tau/3, kx = tau%3;
        const unsigned short* Bsrc = (t < 8 ? Bcur : (const unsigned short*)Bnxt) + (jr0 + ky)*4096;
        #pragma unroll
        for (int n=0;n<4;++n) bfc[n] = *(const bf16x8*)&Bsrc[boff[kx][n]];
        const unsigned short* At = Ash[(t+1)%3];
        #pragma unroll
        for (int m=0;m<9;++m) afc[m] = *(const bf16x8*)&At[Abase + m*512];
      }
      // 5) barrier (reads may span it; buffers safe for 2 more phases)
      __builtin_amdgcn_sched_barrier(0);
      __builtin_amdgcn_s_barrier();
    }
    cA += 9*TILE_USH;
  }

  // epilogue
  const int orow = 2*rp + (wc >> 1);
  const int colb = (wc & 1)*64;
  #pragma unroll
  for (int m=0;m<9;++m){
    int ocb = wr*144 + m*16 + 4*g;            // rows ocb..ocb+3
    if (wr == 0 && m < 6){
      #pragma unroll
      for (int r=0;r<4;++r){
        int oc = ocb + r;
        float bias = b_s[oc];
        #pragma unroll
        for (int n=0;n<4;++n){
          int p = orow*128 + colb + n*16 + cl;
          out[(size_t)(b*96+oc)*HWSZ + p] = acc[m][n][r] + bias;
        }
      }
    } else {
      float2* outv = (float2*)(out + OUT_S_ELEMS);
      int row0 = ocb - 96;                    // even
      int o0 = row0 >> 1;
      float mb0 = MB[b*192+row0  ], mb1 = MB[b*192+row0+1];
      float mb2 = MB[b*192+row0+2], mb3 = MB[b*192+row0+3];
      #pragma unroll
      for (int n=0;n<4;++n){
        int p = orow*128 + colb + n*16 + cl;
        outv[(size_t)(b*96+o0  )*HWSZ + p] = (float2){acc[m][n][0]+mb0, acc[m][n][1]+mb1};
        outv[(size_t)(b*96+o0+1)*HWSZ + p] = (float2){acc[m][n][2]+mb2, acc[m][n][3]+mb3};
      }
    }
  }
}

extern "C" void kernel_launch(void* const* d_in, const int* in_sizes, int n_in,
                              void* d_out, int out_size, void* d_ws, size_t ws_size,
                              hipStream_t stream){
  const float* xs   = (const float*)d_in[0];
  const float* xv   = (const float*)d_in[1];
  const float* f_k0 = (const float*)d_in[2];
  const float* f_k1 = (const float*)d_in[3];
  const float* f_k2 = (const float*)d_in[4];
  const float* w_ss = (const float*)d_in[5];
  const float* w_sv = (const float*)d_in[6];
  const float* w_vs = (const float*)d_in[7];
  const float* w_vv = (const float*)d_in[8];
  const float* b_s  = (const float*)d_in[9];
  const float* b_v  = (const float*)d_in[10];
  float* out = (float*)d_out;

  char* ws = (char*)d_ws;
  unsigned short* WbT = (unsigned short*)ws;                 // 1,492,992 B (+6144 slop)
  const size_t XP_OFF = (size_t)NTILES*TILE_USH*2 + 6144;    // 1,499,136
  unsigned short* Xp = (unsigned short*)(ws + XP_OFF);
  const size_t PART_OFF = XP_OFF + (size_t)8*HWSZ*ICTOT*2;   // + 75,497,472
  float* Part = (float*)(ws + PART_OFF);                     // 2,359,296 B
  float* Ssum = (float*)(ws + PART_OFF + 2359296);           // 9216 B
  float* MB   = (float*)(ws + PART_OFF + 2359296 + 9216);    // 6144 B

  pack_w_kernel<<<(NTILES*ICTOT*32 + 255)/256, 256, 0, stream>>>(
      w_ss, w_sv, w_vs, w_vv, f_k0, f_k1, f_k2, WbT);
  pack_x_kernel<<<12288, 256, 0, stream>>>(xs, xv, Xp, Part);
  reduce_part_kernel<<<8, 320, 0, stream>>>(Part, Ssum);
  mbias_kernel<<<192, 64, 0, stream>>>(w_sv, w_vv, f_k1, f_k2, b_v, Ssum, MB);
  conv_mfma_kernel<<<512, 512, 0, stream>>>(Xp, WbT, b_s, MB, out);
}